// Round 8
// baseline (405.402 us; speedup 1.0000x reference)
//
#include <hip/hip_runtime.h>
#include <cstdint>

// ---------------------------------------------------------------------------
// RegionModel R8: bf16 MFMA implicit-GEMM, channels-last, DEEP-BATCHED LOADS.
// R7 was latency-bound (MfmaUtil 8.7%, HBM 40%, VGPR=64: compiler minimized
// regs -> no pipelining; 9 shallow load->wait->MFMA steps/wave exposed ~900cy
// HBM latency each). R8: per K-slice, issue ALL 9 taps x 4 nt B-loads (36
// independent dwordx4, ~144 VGPR) before any MFMA -> one deep vmcnt drain per
// slice; __launch_bounds__(256,2) gives the allocator the budget. ILP
// replaces TLP; target is the HBM roofline (conv2 ~265 MB ~ 42 us).
// ---------------------------------------------------------------------------

typedef __attribute__((ext_vector_type(8))) short short8;
typedef __attribute__((ext_vector_type(4))) float floatx4;
typedef __attribute__((ext_vector_type(4))) unsigned short ushort4v;

__device__ inline unsigned short f2bf(float f) {
  union { float f; unsigned u; } x;
  x.f = f;
  unsigned u = x.u;
  u += 0x7FFFu + ((u >> 16) & 1u);  // round-to-nearest-even
  return (unsigned short)(u >> 16);
}

__global__ __launch_bounds__(128) void prep_k(const int* __restrict__ rp,
                                              int* __restrict__ rout,
                                              float* __restrict__ feat) {
  __shared__ int is64;
  if (threadIdx.x == 0) {
    int odd_or = 0;
    for (int i = 0; i < 64; ++i) odd_or |= rp[2 * i + 1];
    is64 = (odd_or == 0) ? 1 : 0;
  }
  __syncthreads();
  int b = threadIdx.x;
  int r = is64 ? rp[2 * b] : rp[b];
  rout[b] = r & 7;
  float* fr = feat + b * 128;
  for (int j = 0; j < 128; ++j) fr[j] = 0.f;
}

// conv1 weights -> [r][kg(2)][mt(2)][lane][j] ; k = kg*32+q*8+j maps to
// row = kg*2+(q>>1), idx=(q&1)*8+j, kx=idx>>2, c=idx&3; pad slots -> 0.
__global__ __launch_bounds__(256) void pack1_k(const float* __restrict__ w,
                                               unsigned short* __restrict__ dst) {
  int t = blockIdx.x * blockDim.x + threadIdx.x;
  if (t >= 16384) return;
  int j = t & 7, lane = (t >> 3) & 63, mt = (t >> 9) & 1, kg = (t >> 10) & 1,
      r = t >> 11;
  int oc = mt * 16 + (lane & 15);
  int q = (lane >> 4) & 3;
  int row = kg * 2 + (q >> 1);
  int idx = (q & 1) * 8 + j;
  int kx = idx >> 2, c = idx & 3;
  float val = 0.f;
  if (row < 3 && kx < 3 && c < 3) val = w[((r * 32 + oc) * 3 + c) * 9 + row * 3 + kx];
  dst[t] = f2bf(val);
}

// conv2/3 weights [R][OC][IC][3][3] -> [r][tap][s][mt][lane][j], ic=s*32+q*8+j
template <int OC, int IC, int SUBK, int MTG>
__global__ __launch_bounds__(256) void packT_k(const float* __restrict__ w,
                                               unsigned short* __restrict__ dst) {
  const int total = 8 * 9 * SUBK * MTG * 512;
  int t = blockIdx.x * blockDim.x + threadIdx.x;
  if (t >= total) return;
  int j = t & 7, lane = (t >> 3) & 63;
  int u = t >> 9;
  int mt = u % MTG; u /= MTG;
  int s = u % SUBK; u /= SUBK;
  int tap = u % 9;
  int r = u / 9;
  int oc = mt * 16 + (lane & 15);
  int ic = s * 32 + ((lane >> 4) & 3) * 8 + j;
  dst[t] = f2bf(w[((r * OC + oc) * IC + ic) * 9 + tap]);
}

// fp32 planar image chunk -> padded channels-last bf16 [s][258][258][4]
__global__ __launch_bounds__(256) void imgcvt_k(const float* __restrict__ img,
                                                unsigned short* __restrict__ dst,
                                                int b0, int total) {
  int t = blockIdx.x * blockDim.x + threadIdx.x;
  if (t >= total) return;
  int s = t / (258 * 258);
  int rem = t - s * (258 * 258);
  int y = rem / 258, x = rem - y * 258;
  ushort4v v = {0, 0, 0, 0};
  if (y >= 1 && y <= 256 && x >= 1 && x <= 256) {
    const float* ip = img + ((size_t)(b0 + s) * 3) * 65536 + (y - 1) * 256 + (x - 1);
    v.x = f2bf(ip[0]);
    v.y = f2bf(ip[65536]);
    v.z = f2bf(ip[2 * 65536]);
  }
  *(ushort4v*)(dst + (size_t)t * 4) = v;
}

// zero halo of channels-last buffer [nsamp][HP][WP][IC]
template <int IC>
__global__ __launch_bounds__(256) void haloc_k(unsigned short* __restrict__ buf,
                                               int nsamp, int HP, int WP) {
  int per = 2 * WP + 2 * (HP - 2);
  int t = blockIdx.x * blockDim.x + threadIdx.x;
  if (t >= nsamp * per) return;
  int s = t / per, i = t - s * per;
  int y, x;
  if (i < WP) { y = 0; x = i; }
  else if (i < 2 * WP) { y = HP - 1; x = i - WP; }
  else {
    int ii = i - 2 * WP;
    y = 1 + (ii >> 1);
    x = (ii & 1) ? (WP - 1) : 0;
  }
  unsigned short* p = buf + ((size_t)s * HP * WP + y * WP + x) * IC;
  short8 z = {0, 0, 0, 0, 0, 0, 0, 0};
#pragma unroll
  for (int j = 0; j < IC / 8; ++j) ((short8*)p)[j] = z;
}

// conv1: 3->32, 256->128. imgp [258][258][4] c-last, K = 3 rows x 16.
// Wave = 64 px (4 n-tiles of 16). All 8 B-loads batched before MFMA.
__global__ __launch_bounds__(256, 4) void conv1_k(
    const unsigned short* __restrict__ in, const unsigned short* __restrict__ wp,
    const float* __restrict__ bias, const int* __restrict__ rgn,
    unsigned short* __restrict__ outp, int b0) {
  const int tid = threadIdx.x;
  const int bl = blockIdx.y;
  const int r = __builtin_amdgcn_readfirstlane(rgn[b0 + bl]);
  __shared__ float sBias[32];
  if (tid < 32) sBias[tid] = bias[r * 32 + tid];
  __syncthreads();
  const int lane = tid & 63, n = tid & 15, q = (tid >> 4) & 3;
  const int px0 = (blockIdx.x * 4 + (tid >> 6)) * 64;
  const unsigned short* inb = in + (size_t)bl * 258 * 258 * 4 + (q & 1) * 8;
  int oyA[4], oxA[4];
  const unsigned short* pB[4];
#pragma unroll
  for (int nt = 0; nt < 4; ++nt) {
    int px = px0 + nt * 16 + n;
    oyA[nt] = px >> 7;
    oxA[nt] = px & 127;
    pB[nt] = inb + ((size_t)(2 * oyA[nt]) * 258 + 2 * oxA[nt]) * 4;
  }
  const short8* wpb = (const short8*)wp + (size_t)r * 256 + lane;
  // batch all B loads (2 kg x 4 nt)
  short8 bfr[2][4];
#pragma unroll
  for (int kg = 0; kg < 2; ++kg) {
    int row = kg * 2 + (q >> 1);
    int rowc = (row < 3) ? row : 0;  // pad rows: zero weights, safe addr
#pragma unroll
    for (int nt = 0; nt < 4; ++nt)
      bfr[kg][nt] = *(const short8*)(pB[nt] + (size_t)rowc * 258 * 4);
  }
  short8 afr[2][2];
#pragma unroll
  for (int kg = 0; kg < 2; ++kg)
#pragma unroll
    for (int m = 0; m < 2; ++m) afr[kg][m] = wpb[(kg * 2 + m) * 64];
  floatx4 acc[4][2];
#pragma unroll
  for (int nt = 0; nt < 4; ++nt)
#pragma unroll
    for (int m = 0; m < 2; ++m) acc[nt][m] = (floatx4){0.f, 0.f, 0.f, 0.f};
#pragma unroll
  for (int kg = 0; kg < 2; ++kg)
#pragma unroll
    for (int m = 0; m < 2; ++m)
#pragma unroll
      for (int nt = 0; nt < 4; ++nt)
        acc[nt][m] = __builtin_amdgcn_mfma_f32_16x16x32_bf16(afr[kg][m], bfr[kg][nt],
                                                             acc[nt][m], 0, 0, 0);
  unsigned short* ob = outp + (size_t)bl * 130 * 130 * 32;
#pragma unroll
  for (int nt = 0; nt < 4; ++nt)
#pragma unroll
    for (int m = 0; m < 2; ++m) {
      ushort4v st;
#pragma unroll
      for (int rr = 0; rr < 4; ++rr) {
        float v = acc[nt][m][rr] + sBias[m * 16 + q * 4 + rr];
        st[rr] = f2bf(v > 0.f ? v : 0.f);
      }
      *(ushort4v*)(ob + ((size_t)(oyA[nt] + 1) * 130 + oxA[nt] + 1) * 32 + m * 16 +
                   q * 4) = st;
    }
}

// per-tap MFMA conv, stride 2, channels-last, zero halo, 64 px/wave.
// Per K-slice s: ALL 9x4 B-loads issued first (one deep vmcnt drain), then
// 9 x (A-load + 16 MFMA). blockIdx.x = px block, .y = oc-part, .z = sample.
template <int IC, int OCB, int OCTOT, int OW, int IWP, int SUBK, int OPW, bool GAP>
__global__ __launch_bounds__(256, 2) void convm_k(
    const unsigned short* __restrict__ in, const unsigned short* __restrict__ wp,
    const float* __restrict__ bias, const int* __restrict__ rgn,
    unsigned short* __restrict__ outp, float* __restrict__ feat, int b0) {
  constexpr int MT = OCB / 16;
  constexpr int MTG = OCTOT / 16;
  const int tid = threadIdx.x;
  const int bl = blockIdx.z;
  const int b = b0 + bl;
  const int r = __builtin_amdgcn_readfirstlane(rgn[b]);
  const int ocbase = blockIdx.y * OCB;
  __shared__ float sBias[OCB];
  for (int t = tid; t < OCB; t += 256) sBias[t] = bias[r * OCTOT + ocbase + t];
  __syncthreads();
  const int lane = tid & 63, n = tid & 15, q = (tid >> 4) & 3;
  const int px0 = (blockIdx.x * 4 + (tid >> 6)) * 64;
  const unsigned short* inS = in + (size_t)bl * IC * IWP * IWP + q * 8;
  int oyA[4], oxA[4];
  const unsigned short* pB[4];
#pragma unroll
  for (int nt = 0; nt < 4; ++nt) {
    int px = px0 + nt * 16 + n;
    oyA[nt] = px / OW;
    oxA[nt] = px % OW;
    pB[nt] = inS + ((size_t)(2 * oyA[nt]) * IWP + 2 * oxA[nt]) * IC;
  }
  const short8* wpb = (const short8*)wp + (size_t)r * 9 * SUBK * MTG * 64 + lane;
  floatx4 acc[4][MT];
#pragma unroll
  for (int nt = 0; nt < 4; ++nt)
#pragma unroll
    for (int m = 0; m < MT; ++m) acc[nt][m] = (floatx4){0.f, 0.f, 0.f, 0.f};
#pragma unroll
  for (int s = 0; s < SUBK; ++s) {
    short8 bfr[9][4];  // all taps x nt, batched: 36 independent dwordx4
#pragma unroll
    for (int tap = 0; tap < 9; ++tap) {
      const int ky = tap / 3, kx = tap % 3;
#pragma unroll
      for (int nt = 0; nt < 4; ++nt)
        bfr[tap][nt] =
            *(const short8*)(pB[nt] + (size_t)(ky * IWP + kx) * IC + s * 32);
    }
#pragma unroll
    for (int tap = 0; tap < 9; ++tap) {
      short8 afr[MT];
#pragma unroll
      for (int m = 0; m < MT; ++m)
        afr[m] = wpb[((tap * SUBK + s) * MTG + blockIdx.y * MT + m) * 64];
#pragma unroll
      for (int m = 0; m < MT; ++m)
#pragma unroll
        for (int nt = 0; nt < 4; ++nt)
          acc[nt][m] = __builtin_amdgcn_mfma_f32_16x16x32_bf16(afr[m], bfr[tap][nt],
                                                               acc[nt][m], 0, 0, 0);
    }
  }
  if constexpr (!GAP) {
    unsigned short* ob = outp + (size_t)bl * OCTOT * OPW * OPW;
#pragma unroll
    for (int nt = 0; nt < 4; ++nt)
#pragma unroll
      for (int m = 0; m < MT; ++m) {
        ushort4v st;
#pragma unroll
        for (int rr = 0; rr < 4; ++rr) {
          float v = acc[nt][m][rr] + sBias[m * 16 + q * 4 + rr];
          st[rr] = f2bf(v > 0.f ? v : 0.f);
        }
        *(ushort4v*)(ob + ((size_t)(oyA[nt] + 1) * OPW + oxA[nt] + 1) * OCTOT +
                     ocbase + m * 16 + q * 4) = st;
      }
  } else {
#pragma unroll
    for (int m = 0; m < MT; ++m)
#pragma unroll
      for (int rr = 0; rr < 4; ++rr) {
        float bv = sBias[m * 16 + q * 4 + rr];
        float vs = 0.f;
#pragma unroll
        for (int nt = 0; nt < 4; ++nt) {  // bias+ReLU per pixel, then presum
          float v = acc[nt][m][rr] + bv;
          vs += (v > 0.f ? v : 0.f);
        }
        vs += __shfl_xor(vs, 1, 16);
        vs += __shfl_xor(vs, 2, 16);
        vs += __shfl_xor(vs, 4, 16);
        vs += __shfl_xor(vs, 8, 16);
        if (n == 0)
          atomicAdd(&feat[b * 128 + ocbase + m * 16 + q * 4 + rr], vs);
      }
  }
}

__global__ __launch_bounds__(256) void head_k(
    const float* __restrict__ feat, const float* __restrict__ fw,
    const float* __restrict__ fb, const int* __restrict__ rgn,
    float* __restrict__ out) {
  int t = threadIdx.x;  // 128 samples x 2 classes
  int b = t >> 1, c = t & 1;
  int r = rgn[b];
  const float* fwr = fw + (r * 2 + c) * 128;
  const float* fv = feat + b * 128;
  float a = 0.f;
#pragma unroll 8
  for (int j = 0; j < 128; ++j) a = fmaf(fwr[j], fv[j], a);
  out[t] = a * (1.0f / 1024.0f) + fb[r * 2 + c];
}

extern "C" void kernel_launch(void* const* d_in, const int* in_sizes, int n_in,
                              void* d_out, int out_size, void* d_ws, size_t ws_size,
                              hipStream_t stream) {
  const float* img = (const float*)d_in[0];
  const int* rgn_raw = (const int*)d_in[1];
  const float* w1 = (const float*)d_in[2];
  const float* b1 = (const float*)d_in[3];
  const float* w2 = (const float*)d_in[4];
  const float* b2 = (const float*)d_in[5];
  const float* w3 = (const float*)d_in[6];
  const float* b3 = (const float*)d_in[7];
  const float* fw = (const float*)d_in[8];
  const float* fb = (const float*)d_in[9];
  float* out = (float*)d_out;

  const size_t imgp_s = (size_t)258 * 258 * 4 * 2;   // 532 KB
  const size_t h1p_s = (size_t)130 * 130 * 32 * 2;   // 1.08 MB
  const size_t h2p_s = (size_t)66 * 66 * 64 * 2;     // 557 KB
  const size_t per_sample = imgp_s + h1p_s + h2p_s;  // ~2.17 MB
  const size_t fixed = (size_t)16384 * 2 + (size_t)147456 * 2 +
                       (size_t)589824 * 2 + 128 * 128 * 4 + 512 + 16 * 256;
  int C = 128;
  while (C > 1 && fixed + (size_t)C * per_sample > ws_size) C >>= 1;

  char* ws = (char*)d_ws;
  size_t off = 0;
  auto alloc = [&](size_t bytes) {
    char* p = ws + off;
    off += (bytes + 255) & ~(size_t)255;
    return p;
  };
  unsigned short* imgp = (unsigned short*)alloc((size_t)C * imgp_s);
  unsigned short* h1p = (unsigned short*)alloc((size_t)C * h1p_s);
  unsigned short* h2p = (unsigned short*)alloc((size_t)C * h2p_s);
  unsigned short* w1p = (unsigned short*)alloc((size_t)16384 * 2);
  unsigned short* w2p = (unsigned short*)alloc((size_t)147456 * 2);
  unsigned short* w3p = (unsigned short*)alloc((size_t)589824 * 2);
  float* feat = (float*)alloc((size_t)128 * 128 * 4);
  int* rgn = (int*)alloc((size_t)128 * 4);

  hipLaunchKernelGGL(prep_k, dim3(1), dim3(128), 0, stream, rgn_raw, rgn, feat);
  hipLaunchKernelGGL(pack1_k, dim3(64), dim3(256), 0, stream, w1, w1p);
  hipLaunchKernelGGL((packT_k<64, 32, 1, 4>), dim3(576), dim3(256), 0, stream, w2, w2p);
  hipLaunchKernelGGL((packT_k<128, 64, 2, 8>), dim3(2304), dim3(256), 0, stream, w3, w3p);
  {  // zero halos once; interiors rewritten every chunk
    int n1 = C * (2 * 130 + 2 * 128);
    hipLaunchKernelGGL((haloc_k<32>), dim3((n1 + 255) / 256), dim3(256), 0, stream,
                       h1p, C, 130, 130);
    int n2 = C * (2 * 66 + 2 * 64);
    hipLaunchKernelGGL((haloc_k<64>), dim3((n2 + 255) / 256), dim3(256), 0, stream,
                       h2p, C, 66, 66);
  }

  for (int b0 = 0; b0 < 128; b0 += C) {
    int totimg = C * 258 * 258;
    hipLaunchKernelGGL(imgcvt_k, dim3((totimg + 255) / 256), dim3(256), 0, stream,
                       img, imgp, b0, totimg);
    hipLaunchKernelGGL(conv1_k, dim3(64, C), dim3(256), 0, stream,
                       imgp, w1p, b1, rgn, h1p, b0);
    // conv2: 4096 px / 256 per block = 16 x-blocks, all 64 oc per block
    hipLaunchKernelGGL((convm_k<32, 64, 64, 64, 130, 1, 66, false>),
                       dim3(16, 1, C), dim3(256), 0, stream,
                       h1p, w2p, b2, rgn, h2p, feat, b0);
    // conv3: 1024 px / 256 = 4 x-blocks, 2 oc-halves
    hipLaunchKernelGGL((convm_k<64, 64, 128, 32, 66, 2, 1, true>),
                       dim3(4, 2, C), dim3(256), 0, stream,
                       h2p, w3p, b3, rgn, (unsigned short*)nullptr, feat, b0);
  }
  hipLaunchKernelGGL(head_k, dim3(1), dim3(256), 0, stream, feat, fw, fb, rgn, out);
}

// Round 10
// 364.634 us; speedup vs baseline: 1.1118x; 1.1118x over previous
//
#include <hip/hip_runtime.h>
#include <cstdint>

// ---------------------------------------------------------------------------
// RegionModel R10 = R9 with the staging-width bug fixed.
// R9 NaN'd because LDS staging used ushort4v (8 B) loads for 16 B (8-ch)
// chunks -> odd half of every channel group was uninitialized LDS (garbage
// incl. bf16 NaN patterns). R10 stages with short8 (16 B). Structure:
//  conv2: block = 4 out rows x 64 px; tile 9x130x32ch = 74.9 KB LDS, 1 phase.
//  conv3: block = 8 out rows x 32 px; tile 17x66x32ch = 71.8 KB x 2 K-phases,
//         all 128 oc in one pass (acc = 128 AGPR) -> h2 read ONCE.
// Tile layout [row][c8][x][8ch]; B-frag = one ds_read_b128. A from L2.
// conv1 register-batched (R8 form). GAP fused in conv3. ws-adaptive chunks.
// ---------------------------------------------------------------------------

typedef __attribute__((ext_vector_type(8))) short short8;
typedef __attribute__((ext_vector_type(4))) float floatx4;
typedef __attribute__((ext_vector_type(4))) unsigned short ushort4v;

__device__ inline unsigned short f2bf(float f) {
  union { float f; unsigned u; } x;
  x.f = f;
  unsigned u = x.u;
  u += 0x7FFFu + ((u >> 16) & 1u);  // round-to-nearest-even
  return (unsigned short)(u >> 16);
}

__global__ __launch_bounds__(128) void prep_k(const int* __restrict__ rp,
                                              int* __restrict__ rout,
                                              float* __restrict__ feat) {
  __shared__ int is64;
  if (threadIdx.x == 0) {
    int odd_or = 0;
    for (int i = 0; i < 64; ++i) odd_or |= rp[2 * i + 1];
    is64 = (odd_or == 0) ? 1 : 0;
  }
  __syncthreads();
  int b = threadIdx.x;
  int r = is64 ? rp[2 * b] : rp[b];
  rout[b] = r & 7;
  float* fr = feat + b * 128;
  for (int j = 0; j < 128; ++j) fr[j] = 0.f;
}

// conv1 weights -> [r][kg(2)][mt(2)][lane][j] ; k = kg*32+q*8+j maps to
// row = kg*2+(q>>1), idx=(q&1)*8+j, kx=idx>>2, c=idx&3; pad slots -> 0.
__global__ __launch_bounds__(256) void pack1_k(const float* __restrict__ w,
                                               unsigned short* __restrict__ dst) {
  int t = blockIdx.x * blockDim.x + threadIdx.x;
  if (t >= 16384) return;
  int j = t & 7, lane = (t >> 3) & 63, mt = (t >> 9) & 1, kg = (t >> 10) & 1,
      r = t >> 11;
  int oc = mt * 16 + (lane & 15);
  int q = (lane >> 4) & 3;
  int row = kg * 2 + (q >> 1);
  int idx = (q & 1) * 8 + j;
  int kx = idx >> 2, c = idx & 3;
  float val = 0.f;
  if (row < 3 && kx < 3 && c < 3) val = w[((r * 32 + oc) * 3 + c) * 9 + row * 3 + kx];
  dst[t] = f2bf(val);
}

// conv2/3 weights [R][OC][IC][3][3] -> [r][tap][s][mt][lane][j], ic=s*32+q*8+j
template <int OC, int IC, int SUBK, int MTG>
__global__ __launch_bounds__(256) void packT_k(const float* __restrict__ w,
                                               unsigned short* __restrict__ dst) {
  const int total = 8 * 9 * SUBK * MTG * 512;
  int t = blockIdx.x * blockDim.x + threadIdx.x;
  if (t >= total) return;
  int j = t & 7, lane = (t >> 3) & 63;
  int u = t >> 9;
  int mt = u % MTG; u /= MTG;
  int s = u % SUBK; u /= SUBK;
  int tap = u % 9;
  int r = u / 9;
  int oc = mt * 16 + (lane & 15);
  int ic = s * 32 + ((lane >> 4) & 3) * 8 + j;
  dst[t] = f2bf(w[((r * OC + oc) * IC + ic) * 9 + tap]);
}

// fp32 planar image chunk -> padded channels-last bf16 [s][258][258][4]
__global__ __launch_bounds__(256) void imgcvt_k(const float* __restrict__ img,
                                                unsigned short* __restrict__ dst,
                                                int b0, int total) {
  int t = blockIdx.x * blockDim.x + threadIdx.x;
  if (t >= total) return;
  int s = t / (258 * 258);
  int rem = t - s * (258 * 258);
  int y = rem / 258, x = rem - y * 258;
  ushort4v v = {0, 0, 0, 0};
  if (y >= 1 && y <= 256 && x >= 1 && x <= 256) {
    const float* ip = img + ((size_t)(b0 + s) * 3) * 65536 + (y - 1) * 256 + (x - 1);
    v.x = f2bf(ip[0]);
    v.y = f2bf(ip[65536]);
    v.z = f2bf(ip[2 * 65536]);
  }
  *(ushort4v*)(dst + (size_t)t * 4) = v;
}

// zero halo of channels-last buffer [nsamp][HP][WP][IC]
template <int IC>
__global__ __launch_bounds__(256) void haloc_k(unsigned short* __restrict__ buf,
                                               int nsamp, int HP, int WP) {
  int per = 2 * WP + 2 * (HP - 2);
  int t = blockIdx.x * blockDim.x + threadIdx.x;
  if (t >= nsamp * per) return;
  int s = t / per, i = t - s * per;
  int y, x;
  if (i < WP) { y = 0; x = i; }
  else if (i < 2 * WP) { y = HP - 1; x = i - WP; }
  else {
    int ii = i - 2 * WP;
    y = 1 + (ii >> 1);
    x = (ii & 1) ? (WP - 1) : 0;
  }
  unsigned short* p = buf + ((size_t)s * HP * WP + y * WP + x) * IC;
  short8 z = {0, 0, 0, 0, 0, 0, 0, 0};
#pragma unroll
  for (int j = 0; j < IC / 8; ++j) ((short8*)p)[j] = z;
}

// conv1: 3->32, 256->128. imgp [258][258][4] c-last, K = 3 rows x 16.
// Wave = 64 px (4 n-tiles of 16), B loads batched.
__global__ __launch_bounds__(256, 4) void conv1_k(
    const unsigned short* __restrict__ in, const unsigned short* __restrict__ wp,
    const float* __restrict__ bias, const int* __restrict__ rgn,
    unsigned short* __restrict__ outp, int b0) {
  const int tid = threadIdx.x;
  const int bl = blockIdx.y;
  const int r = __builtin_amdgcn_readfirstlane(rgn[b0 + bl]);
  __shared__ float sBias[32];
  if (tid < 32) sBias[tid] = bias[r * 32 + tid];
  __syncthreads();
  const int n = tid & 15, q = (tid >> 4) & 3;
  const int lane = tid & 63;
  const int px0 = (blockIdx.x * 4 + (tid >> 6)) * 64;
  const unsigned short* inb = in + (size_t)bl * 258 * 258 * 4 + (q & 1) * 8;
  int oyA[4], oxA[4];
  const unsigned short* pB[4];
#pragma unroll
  for (int nt = 0; nt < 4; ++nt) {
    int px = px0 + nt * 16 + n;
    oyA[nt] = px >> 7;
    oxA[nt] = px & 127;
    pB[nt] = inb + ((size_t)(2 * oyA[nt]) * 258 + 2 * oxA[nt]) * 4;
  }
  const short8* wpb = (const short8*)wp + (size_t)r * 256 + lane;
  short8 bfr[2][4];
#pragma unroll
  for (int kg = 0; kg < 2; ++kg) {
    int row = kg * 2 + (q >> 1);
    int rowc = (row < 3) ? row : 0;  // pad rows: zero weights, safe addr
#pragma unroll
    for (int nt = 0; nt < 4; ++nt)
      bfr[kg][nt] = *(const short8*)(pB[nt] + (size_t)rowc * 258 * 4);
  }
  short8 afr[2][2];
#pragma unroll
  for (int kg = 0; kg < 2; ++kg)
#pragma unroll
    for (int m = 0; m < 2; ++m) afr[kg][m] = wpb[(kg * 2 + m) * 64];
  floatx4 acc[4][2];
#pragma unroll
  for (int nt = 0; nt < 4; ++nt)
#pragma unroll
    for (int m = 0; m < 2; ++m) acc[nt][m] = (floatx4){0.f, 0.f, 0.f, 0.f};
#pragma unroll
  for (int kg = 0; kg < 2; ++kg)
#pragma unroll
    for (int m = 0; m < 2; ++m)
#pragma unroll
      for (int nt = 0; nt < 4; ++nt)
        acc[nt][m] = __builtin_amdgcn_mfma_f32_16x16x32_bf16(afr[kg][m], bfr[kg][nt],
                                                             acc[nt][m], 0, 0, 0);
  unsigned short* ob = outp + (size_t)bl * 130 * 130 * 32;
#pragma unroll
  for (int nt = 0; nt < 4; ++nt)
#pragma unroll
    for (int m = 0; m < 2; ++m) {
      ushort4v st;
#pragma unroll
      for (int rr = 0; rr < 4; ++rr) {
        float v = acc[nt][m][rr] + sBias[m * 16 + q * 4 + rr];
        st[rr] = f2bf(v > 0.f ? v : 0.f);
      }
      *(ushort4v*)(ob + ((size_t)(oyA[nt] + 1) * 130 + oxA[nt] + 1) * 32 + m * 16 +
                   q * 4) = st;
    }
}

// conv2: 32->64, 64x64 out. Block = 4 out rows x 64 px; wave w = row oy0+w.
// LDS tile [9 rows][c8 0..3][130 x][8ch] staged once, K-loop from LDS.
__global__ __launch_bounds__(256, 2) void conv2lds_k(
    const unsigned short* __restrict__ in, const unsigned short* __restrict__ wp,
    const float* __restrict__ bias, const int* __restrict__ rgn,
    unsigned short* __restrict__ outp, int b0) {
  __shared__ unsigned short tile[9 * 4 * 130 * 8];  // 74,880 B
  __shared__ float sBias[64];
  const int tid = threadIdx.x;
  const int bl = blockIdx.y;
  const int r = __builtin_amdgcn_readfirstlane(rgn[b0 + bl]);
  if (tid < 64) sBias[tid] = bias[r * 64 + tid];
  const int oy0 = blockIdx.x * 4;
  const unsigned short* gsrc =
      in + (size_t)bl * 130 * 130 * 32 + (size_t)(2 * oy0) * 130 * 32;
  // stage: 4680 chunks of 8ch (16 B = short8), grouped 4-deep for VMEM flight
  for (int base = 0; base < 4680; base += 4 * 256) {
    short8 tmp[4];
#pragma unroll
    for (int i = 0; i < 4; ++i) {
      int c = base + i * 256 + tid;
      if (c < 4680) tmp[i] = *(const short8*)(gsrc + (size_t)c * 8);
    }
#pragma unroll
    for (int i = 0; i < 4; ++i) {
      int c = base + i * 256 + tid;
      if (c < 4680) {
        int row = c / 520;
        int rem = c - row * 520;
        int x = rem >> 2, c8 = rem & 3;
        *(short8*)&tile[(((row << 2) + c8) * 130 + x) * 8] = tmp[i];
      }
    }
  }
  __syncthreads();
  const int n = tid & 15, q = (tid >> 4) & 3, w = tid >> 6;
  const short8* wpb = (const short8*)wp + (size_t)r * 9 * 4 * 64 + (tid & 63);
  floatx4 acc[4][4];
#pragma unroll
  for (int nt = 0; nt < 4; ++nt)
#pragma unroll
    for (int m = 0; m < 4; ++m) acc[nt][m] = (floatx4){0.f, 0.f, 0.f, 0.f};
#pragma unroll
  for (int tap = 0; tap < 9; ++tap) {
    const int ky = tap / 3, kx = tap % 3;
    short8 afr[4];
#pragma unroll
    for (int m = 0; m < 4; ++m) afr[m] = wpb[(tap * 4 + m) * 64];
    short8 bfr[4];
#pragma unroll
    for (int nt = 0; nt < 4; ++nt) {
      int ox = nt * 16 + n;
      bfr[nt] = *(const short8*)&tile[((((2 * w + ky) << 2) + q) * 130 +
                                      (2 * ox + kx)) * 8];
    }
#pragma unroll
    for (int m = 0; m < 4; ++m)
#pragma unroll
      for (int nt = 0; nt < 4; ++nt)
        acc[nt][m] = __builtin_amdgcn_mfma_f32_16x16x32_bf16(afr[m], bfr[nt],
                                                             acc[nt][m], 0, 0, 0);
  }
  unsigned short* ob = outp + (size_t)bl * 66 * 66 * 64;
  const int oy = oy0 + w;
#pragma unroll
  for (int nt = 0; nt < 4; ++nt) {
    int ox = nt * 16 + n;
#pragma unroll
    for (int m = 0; m < 4; ++m) {
      ushort4v st;
#pragma unroll
      for (int rr = 0; rr < 4; ++rr) {
        float v = acc[nt][m][rr] + sBias[m * 16 + q * 4 + rr];
        st[rr] = f2bf(v > 0.f ? v : 0.f);
      }
      *(ushort4v*)(ob + ((size_t)(oy + 1) * 66 + ox + 1) * 64 + m * 16 + q * 4) = st;
    }
  }
}

// conv3: 64->128, 32x32 out, fused bias+ReLU+GAP. Block = 8 out rows x 32 px
// (256 px); wave w = 2 rows. ALL 128 oc in one pass (acc = 128 AGPR).
// Two K-phases (ch 0..31, 32..63); LDS tile [17][c8 0..3][66][8ch] per phase.
__global__ __launch_bounds__(256, 2) void conv3lds_k(
    const unsigned short* __restrict__ in, const unsigned short* __restrict__ wp,
    const float* __restrict__ bias, const int* __restrict__ rgn,
    float* __restrict__ feat, int b0) {
  __shared__ unsigned short tile[17 * 4 * 66 * 8];  // 71,808 B
  __shared__ float sBias[128];
  const int tid = threadIdx.x;
  const int bl = blockIdx.y;
  const int b = b0 + bl;
  const int r = __builtin_amdgcn_readfirstlane(rgn[b]);
  if (tid < 128) sBias[tid] = bias[r * 128 + tid];
  const int oy0 = blockIdx.x * 8;
  const unsigned short* gbase =
      in + (size_t)bl * 66 * 66 * 64 + (size_t)(2 * oy0) * 66 * 64;
  const int n = tid & 15, q = (tid >> 4) & 3, w = tid >> 6;
  const short8* wpb = (const short8*)wp + (size_t)r * 9 * 2 * 8 * 64 + (tid & 63);
  floatx4 acc[4][8];
#pragma unroll
  for (int nt = 0; nt < 4; ++nt)
#pragma unroll
    for (int m = 0; m < 8; ++m) acc[nt][m] = (floatx4){0.f, 0.f, 0.f, 0.f};
#pragma unroll
  for (int s = 0; s < 2; ++s) {
    __syncthreads();  // previous phase's reads done before restage
    for (int base = 0; base < 4488; base += 4 * 256) {
      short8 tmp[4];
#pragma unroll
      for (int i = 0; i < 4; ++i) {
        int c = base + i * 256 + tid;
        if (c < 4488) {
          int rx = c >> 2, c8 = c & 3;
          tmp[i] = *(const short8*)(gbase + (size_t)rx * 64 + s * 32 + c8 * 8);
        }
      }
#pragma unroll
      for (int i = 0; i < 4; ++i) {
        int c = base + i * 256 + tid;
        if (c < 4488) {
          int rx = c >> 2, c8 = c & 3;
          int row = rx / 66, x = rx - row * 66;
          *(short8*)&tile[(((row << 2) + c8) * 66 + x) * 8] = tmp[i];
        }
      }
    }
    __syncthreads();
#pragma unroll
    for (int tap = 0; tap < 9; ++tap) {
      const int ky = tap / 3, kx = tap % 3;
      short8 afr[8];
#pragma unroll
      for (int m = 0; m < 8; ++m) afr[m] = wpb[((tap * 2 + s) * 8 + m) * 64];
      short8 bfr[4];
#pragma unroll
      for (int nt = 0; nt < 4; ++nt) {
        int rlo = 2 * (w * 2 + (nt >> 1)) + ky;  // input row local 0..16
        int ox = ((nt & 1) << 4) + n;
        bfr[nt] = *(const short8*)&tile[(((rlo << 2) + q) * 66 + (2 * ox + kx)) * 8];
      }
#pragma unroll
      for (int m = 0; m < 8; ++m)
#pragma unroll
        for (int nt = 0; nt < 4; ++nt)
          acc[nt][m] = __builtin_amdgcn_mfma_f32_16x16x32_bf16(afr[m], bfr[nt],
                                                               acc[nt][m], 0, 0, 0);
    }
  }
  // bias + ReLU + GAP partial reduce
#pragma unroll
  for (int m = 0; m < 8; ++m)
#pragma unroll
    for (int rr = 0; rr < 4; ++rr) {
      float bv = sBias[m * 16 + q * 4 + rr];
      float vs = 0.f;
#pragma unroll
      for (int nt = 0; nt < 4; ++nt) {
        float v = acc[nt][m][rr] + bv;
        vs += (v > 0.f ? v : 0.f);
      }
      vs += __shfl_xor(vs, 1, 16);
      vs += __shfl_xor(vs, 2, 16);
      vs += __shfl_xor(vs, 4, 16);
      vs += __shfl_xor(vs, 8, 16);
      if (n == 0) atomicAdd(&feat[b * 128 + m * 16 + q * 4 + rr], vs);
    }
}

__global__ __launch_bounds__(256) void head_k(
    const float* __restrict__ feat, const float* __restrict__ fw,
    const float* __restrict__ fb, const int* __restrict__ rgn,
    float* __restrict__ out) {
  int t = threadIdx.x;  // 128 samples x 2 classes
  int b = t >> 1, c = t & 1;
  int r = rgn[b];
  const float* fwr = fw + (r * 2 + c) * 128;
  const float* fv = feat + b * 128;
  float a = 0.f;
#pragma unroll 8
  for (int j = 0; j < 128; ++j) a = fmaf(fwr[j], fv[j], a);
  out[t] = a * (1.0f / 1024.0f) + fb[r * 2 + c];
}

extern "C" void kernel_launch(void* const* d_in, const int* in_sizes, int n_in,
                              void* d_out, int out_size, void* d_ws, size_t ws_size,
                              hipStream_t stream) {
  const float* img = (const float*)d_in[0];
  const int* rgn_raw = (const int*)d_in[1];
  const float* w1 = (const float*)d_in[2];
  const float* b1 = (const float*)d_in[3];
  const float* w2 = (const float*)d_in[4];
  const float* b2 = (const float*)d_in[5];
  const float* w3 = (const float*)d_in[6];
  const float* b3 = (const float*)d_in[7];
  const float* fw = (const float*)d_in[8];
  const float* fb = (const float*)d_in[9];
  float* out = (float*)d_out;

  const size_t imgp_s = (size_t)258 * 258 * 4 * 2;   // 532 KB
  const size_t h1p_s = (size_t)130 * 130 * 32 * 2;   // 1.08 MB
  const size_t h2p_s = (size_t)66 * 66 * 64 * 2;     // 557 KB
  const size_t per_sample = imgp_s + h1p_s + h2p_s;  // ~2.17 MB
  const size_t fixed = (size_t)16384 * 2 + (size_t)147456 * 2 +
                       (size_t)589824 * 2 + 128 * 128 * 4 + 512 + 16 * 256;
  int C = 128;
  while (C > 1 && fixed + (size_t)C * per_sample > ws_size) C >>= 1;

  char* ws = (char*)d_ws;
  size_t off = 0;
  auto alloc = [&](size_t bytes) {
    char* p = ws + off;
    off += (bytes + 255) & ~(size_t)255;
    return p;
  };
  unsigned short* imgp = (unsigned short*)alloc((size_t)C * imgp_s);
  unsigned short* h1p = (unsigned short*)alloc((size_t)C * h1p_s);
  unsigned short* h2p = (unsigned short*)alloc((size_t)C * h2p_s);
  unsigned short* w1p = (unsigned short*)alloc((size_t)16384 * 2);
  unsigned short* w2p = (unsigned short*)alloc((size_t)147456 * 2);
  unsigned short* w3p = (unsigned short*)alloc((size_t)589824 * 2);
  float* feat = (float*)alloc((size_t)128 * 128 * 4);
  int* rgn = (int*)alloc((size_t)128 * 4);

  hipLaunchKernelGGL(prep_k, dim3(1), dim3(128), 0, stream, rgn_raw, rgn, feat);
  hipLaunchKernelGGL(pack1_k, dim3(64), dim3(256), 0, stream, w1, w1p);
  hipLaunchKernelGGL((packT_k<64, 32, 1, 4>), dim3(576), dim3(256), 0, stream, w2, w2p);
  hipLaunchKernelGGL((packT_k<128, 64, 2, 8>), dim3(2304), dim3(256), 0, stream, w3, w3p);
  {  // zero halos once; interiors rewritten every chunk
    int n1 = C * (2 * 130 + 2 * 128);
    hipLaunchKernelGGL((haloc_k<32>), dim3((n1 + 255) / 256), dim3(256), 0, stream,
                       h1p, C, 130, 130);
    int n2 = C * (2 * 66 + 2 * 64);
    hipLaunchKernelGGL((haloc_k<64>), dim3((n2 + 255) / 256), dim3(256), 0, stream,
                       h2p, C, 66, 66);
  }

  for (int b0 = 0; b0 < 128; b0 += C) {
    int totimg = C * 258 * 258;
    hipLaunchKernelGGL(imgcvt_k, dim3((totimg + 255) / 256), dim3(256), 0, stream,
                       img, imgp, b0, totimg);
    hipLaunchKernelGGL(conv1_k, dim3(64, C), dim3(256), 0, stream,
                       imgp, w1p, b1, rgn, h1p, b0);
    // conv2: 16 row-group blocks (4 rows x 64 px each) per sample
    hipLaunchKernelGGL(conv2lds_k, dim3(16, C), dim3(256), 0, stream,
                       h1p, w2p, b2, rgn, h2p, b0);
    // conv3: 4 row-group blocks (8 rows x 32 px each) per sample
    hipLaunchKernelGGL(conv3lds_k, dim3(4, C), dim3(256), 0, stream,
                       h2p, w3p, b3, rgn, feat, b0);
  }
  hipLaunchKernelGGL(head_k, dim3(1), dim3(256), 0, stream, feat, fw, fb, rgn, out);
}